// Round 1
// baseline (354.567 us; speedup 1.0000x reference)
//
#include <hip/hip_runtime.h>
#include <cstdio>
#include <cstdint>

typedef unsigned short u16;
typedef __bf16 bf16x8 __attribute__((ext_vector_type(8)));
typedef float floatx4 __attribute__((ext_vector_type(4)));

// ---------------- constants ----------------
#define BB 16
#define PP 2048
#define EE 768
#define HH 256
#define PE (PP * EE)          // 1572864
#define MM (BB * PP)          // 32768

__device__ __forceinline__ u16 f2bf(float f) {
  union { float f; uint32_t u; } v; v.f = f;
  return (u16)((v.u + 0x7fffu + ((v.u >> 16) & 1u)) >> 16);
}

__device__ __forceinline__ void gload16(const void* g, void* l) {
  typedef __attribute__((address_space(1))) const void GV;
  typedef __attribute__((address_space(3))) void LV;
  __builtin_amdgcn_global_load_lds((GV*)g, (LV*)l, 16, 0, 0);
}

// ---- 128x128-tile TN GEMM core: A[M][K] rowmajor(lda), B[N][K] rowmajor(ldb),
// BK=64, 256 threads = 4 waves (2x2), each wave 64x64 = 4x4 frags of 16x16x32.
__device__ __forceinline__ void zero_acc(floatx4 acc[4][4]) {
  const floatx4 z = {0.f, 0.f, 0.f, 0.f};
#pragma unroll
  for (int i = 0; i < 4; ++i)
#pragma unroll
    for (int j = 0; j < 4; ++j) acc[i][j] = z;
}

__device__ __forceinline__ void gemm_core(const u16* A, int lda, const u16* B, int ldb,
                                          int kIters, u16* As, u16* Bs,
                                          floatx4 acc[4][4]) {
  const int tid  = threadIdx.x;
  const int lane = tid & 63;
  const int wr   = (tid >> 7) & 1;
  const int wc   = (tid >> 6) & 1;
  const int srow = tid >> 3;           // 0..31
  const int scol = (tid & 7) << 3;     // 0..56
  const int mrow = lane & 15;
  const int kgrp = (lane >> 4) << 3;   // 0,8,16,24
  for (int kk = 0; kk < kIters; ++kk) {
    const u16* Ak = A + kk * 64;
    const u16* Bk = B + kk * 64;
    __syncthreads();  // previous compute done before LDS overwrite
#pragma unroll
    for (int r = 0; r < 4; ++r) {
      gload16(Ak + (size_t)(r * 32 + srow) * lda + scol, (char*)As + r * 4096 + tid * 16);
      gload16(Bk + (size_t)(r * 32 + srow) * ldb + scol, (char*)Bs + r * 4096 + tid * 16);
    }
    __syncthreads();  // compiler drains vmcnt before barrier
#pragma unroll
    for (int kp = 0; kp < 2; ++kp) {
      const int ko = kp * 32 + kgrp;
      bf16x8 af[4], bq[4];
#pragma unroll
      for (int i = 0; i < 4; ++i) {
        af[i] = *(const bf16x8*)(As + (wr * 64 + i * 16 + mrow) * 64 + ko);
        bq[i] = *(const bf16x8*)(Bs + (wc * 64 + i * 16 + mrow) * 64 + ko);
      }
#pragma unroll
      for (int i = 0; i < 4; ++i)
#pragma unroll
        for (int j = 0; j < 4; ++j)
          acc[i][j] = __builtin_amdgcn_mfma_f32_16x16x32_bf16(af[i], bq[j], acc[i][j], 0, 0, 0);
    }
  }
}

template <typename F>
__device__ __forceinline__ void epilogue(floatx4 acc[4][4], F f) {
  const int lane = threadIdx.x & 63;
  const int wr = (threadIdx.x >> 7) & 1, wc = (threadIdx.x >> 6) & 1;
  const int r0 = (lane >> 4) * 4, c0 = lane & 15;
#pragma unroll
  for (int i = 0; i < 4; ++i)
#pragma unroll
    for (int j = 0; j < 4; ++j)
#pragma unroll
      for (int r = 0; r < 4; ++r)
        f(wr * 64 + i * 16 + r0 + r, wc * 64 + j * 16 + c0, acc[i][j][r]);
}

// ---------------- LayerNorm ----------------
__global__ __launch_bounds__(256) void k_reduce1(const float* __restrict__ x,
                                                 float* __restrict__ psum,
                                                 float* __restrict__ psq) {
  const int b = blockIdx.y, blk = blockIdx.x, tid = threadIdx.x;
  const float4* xb = (const float4*)(x + (size_t)b * PE + (size_t)blk * 12288);
  float s = 0.f, q = 0.f;
#pragma unroll
  for (int i = 0; i < 12; ++i) {
    float4 v = xb[tid + i * 256];
    s += v.x + v.y + v.z + v.w;
    q += v.x * v.x + v.y * v.y + v.z * v.z + v.w * v.w;
  }
  for (int off = 32; off > 0; off >>= 1) { s += __shfl_down(s, off); q += __shfl_down(q, off); }
  __shared__ float ls[4], lq[4];
  if ((tid & 63) == 0) { ls[tid >> 6] = s; lq[tid >> 6] = q; }
  __syncthreads();
  if (tid == 0) {
    psum[b * 128 + blk] = ls[0] + ls[1] + ls[2] + ls[3];
    psq [b * 128 + blk] = lq[0] + lq[1] + lq[2] + lq[3];
  }
}

__global__ void k_reduce2(const float* __restrict__ psum, const float* __restrict__ psq,
                          float* __restrict__ stats) {
  const int b = blockIdx.x, tid = threadIdx.x;  // 128 threads
  float s = psum[b * 128 + tid], q = psq[b * 128 + tid];
  for (int off = 32; off > 0; off >>= 1) { s += __shfl_down(s, off); q += __shfl_down(q, off); }
  __shared__ float ls[2], lq[2];
  if ((tid & 63) == 0) { ls[tid >> 6] = s; lq[tid >> 6] = q; }
  __syncthreads();
  if (tid == 0) {
    float S = ls[0] + ls[1], Q = lq[0] + lq[1];
    const float invN = 1.f / (float)PE;
    float mean = S * invN;
    float var = Q * invN - mean * mean;
    stats[b * 2] = mean;
    stats[b * 2 + 1] = rsqrtf(var + 1e-5f);
  }
}

__global__ __launch_bounds__(256) void k_ln(const float* __restrict__ x,
                                            const float* __restrict__ w,
                                            const float* __restrict__ bia,
                                            const float* __restrict__ stats,
                                            u16* __restrict__ xn) {
  const float4* x4 = (const float4*)x;
  const float4* w4 = (const float4*)w;
  const float4* b4 = (const float4*)bia;
  for (int vi = blockIdx.x * 256 + threadIdx.x; vi < (PE / 4) * BB; vi += gridDim.x * 256) {
    int bidx = vi / (PE / 4);
    int wi = vi - bidx * (PE / 4);
    float4 xv = x4[vi], wv = w4[wi], bv = b4[wi];
    float mean = stats[bidx * 2], rstd = stats[bidx * 2 + 1];
    ushort4 o;
    o.x = f2bf((xv.x - mean) * rstd * wv.x + bv.x);
    o.y = f2bf((xv.y - mean) * rstd * wv.y + bv.y);
    o.z = f2bf((xv.z - mean) * rstd * wv.z + bv.z);
    o.w = f2bf((xv.w - mean) * rstd * wv.w + bv.w);
    ((ushort4*)xn)[vi] = o;
  }
}

// ---------------- weight prep ----------------
// qkv_w [E][3H] fp32 -> wT [n][e] bf16 (transposed)
__global__ void k_transpose_w(const float* __restrict__ src, u16* __restrict__ dst) {
  __shared__ float t[32][33];
  const int e0 = blockIdx.x * 32, n0 = blockIdx.y * 32;
  const int tx = threadIdx.x, ty = threadIdx.y;  // 32x8
#pragma unroll
  for (int j = 0; j < 4; ++j)
    t[ty + j * 8][tx] = src[(size_t)(e0 + ty + j * 8) * 768 + n0 + tx];
  __syncthreads();
#pragma unroll
  for (int j = 0; j < 4; ++j)
    dst[(size_t)(n0 + ty + j * 8) * 768 + e0 + tx] = f2bf(t[tx][ty + j * 8]);
}

__global__ void k_cast(const float* __restrict__ src, u16* __restrict__ dst, int n4) {
  int i = blockIdx.x * 256 + threadIdx.x;
  if (i < n4) {
    float4 v = ((const float4*)src)[i];
    ushort4 o;
    o.x = f2bf(v.x); o.y = f2bf(v.y); o.z = f2bf(v.z); o.w = f2bf(v.w);
    ((ushort4*)dst)[i] = o;
  }
}

// ---------------- GEMM wrappers ----------------
__global__ __launch_bounds__(256) void k_gemm_qkv(const u16* __restrict__ xn,
                                                  const u16* __restrict__ wT,
                                                  u16* __restrict__ qkv) {
  __shared__ __align__(16) u16 As[128 * 64], Bs[128 * 64];
  floatx4 acc[4][4];
  zero_acc(acc);
  const int tM = blockIdx.y * 128, tN = blockIdx.x * 128;
  gemm_core(xn + (size_t)tM * EE, EE, wT + (size_t)tN * EE, EE, 12, As, Bs, acc);
  epilogue(acc, [&](int gr, int gc, float v) {
    qkv[(size_t)(tM + gr) * EE + tN + gc] = f2bf(v);
  });
}

// k,v [p][d] -> kT,vT [d][p] per batch
__global__ void k_transpose_kv(const u16* __restrict__ qkv, u16* __restrict__ kT,
                               u16* __restrict__ vT) {
  __shared__ u16 t[32][33];
  const int z = blockIdx.z, b = z >> 1, which = z & 1;
  const int p0 = blockIdx.x * 32, d0 = blockIdx.y * 32;
  const u16* src = qkv + (size_t)b * PE + HH + which * HH;
  u16* dst = (which ? vT : kT) + (size_t)b * (HH * PP);
  const int tx = threadIdx.x, ty = threadIdx.y;
#pragma unroll
  for (int j = 0; j < 4; ++j)
    t[ty + j * 8][tx] = src[(size_t)(p0 + ty + j * 8) * EE + d0 + tx];
  __syncthreads();
#pragma unroll
  for (int j = 0; j < 4; ++j)
    dst[(size_t)(d0 + ty + j * 8) * PP + p0 + tx] = t[tx][ty + j * 8];
}

// Wt[d][b2] = sum_p vT[d][p] kT[b2][p]  (split-K=8 fp32 partials)
__global__ __launch_bounds__(256) void k_gemm_wt(const u16* __restrict__ vT,
                                                 const u16* __restrict__ kT,
                                                 float* __restrict__ part) {
  __shared__ __align__(16) u16 As[128 * 64], Bs[128 * 64];
  floatx4 acc[4][4];
  zero_acc(acc);
  const int z = blockIdx.z, b = z >> 3, s = z & 7;
  const int tM = blockIdx.y * 128, tN = blockIdx.x * 128;
  const u16* A = vT + (size_t)b * (HH * PP) + (size_t)tM * PP + s * 256;
  const u16* B = kT + (size_t)b * (HH * PP) + (size_t)tN * PP + s * 256;
  gemm_core(A, PP, B, PP, 4, As, Bs, acc);
  float* P = part + (size_t)z * 65536;
  epilogue(acc, [&](int gr, int gc, float v) {
    P[(size_t)(tM + gr) * 256 + tN + gc] = v;
  });
}

__global__ void k_reduce_wt(const float* __restrict__ part, u16* __restrict__ Wt) {
  const int idx = blockIdx.x * 256 + threadIdx.x;  // < 16*256*256
  const int b = idx >> 16, i = idx & 65535;
  const float* p = part + ((size_t)b << 19) + i;
  float s = 0.f;
#pragma unroll
  for (int t = 0; t < 8; ++t) s += p[(size_t)t << 16];
  Wt[idx] = f2bf(s);
}

// o[p][d] = sum_b2 q[p][b2] * Wt[d][b2]
__global__ __launch_bounds__(256) void k_gemm_o(const u16* __restrict__ qkv,
                                                const u16* __restrict__ Wt,
                                                u16* __restrict__ o) {
  __shared__ __align__(16) u16 As[128 * 64], Bs[128 * 64];
  floatx4 acc[4][4];
  zero_acc(acc);
  const int b = blockIdx.z;
  const int tM = blockIdx.y * 128, tN = blockIdx.x * 128;
  const u16* A = qkv + (size_t)b * PE + (size_t)tM * EE;  // q = cols 0..255
  const u16* B = Wt + (size_t)b * 65536 + (size_t)tN * 256;
  gemm_core(A, EE, B, 256, 4, As, Bs, acc);
  u16* ob = o + (size_t)b * (PP * HH);
  epilogue(acc, [&](int gr, int gc, float v) {
    ob[(size_t)(tM + gr) * HH + tN + gc] = f2bf(v);
  });
}

// out[p][e] = relu(sum_h o[p][h]*lin_w[e][h] + lin_b[e])
__global__ __launch_bounds__(256) void k_gemm_lin(const u16* __restrict__ o,
                                                  const u16* __restrict__ lw,
                                                  const float* __restrict__ lb,
                                                  float* __restrict__ out) {
  __shared__ __align__(16) u16 As[128 * 64], Bs[128 * 64];
  floatx4 acc[4][4];
  zero_acc(acc);
  const int tM = blockIdx.y * 128, tN = blockIdx.x * 128;
  gemm_core(o + (size_t)tM * HH, HH, lw + (size_t)tN * HH, HH, 4, As, Bs, acc);
  epilogue(acc, [&](int gr, int gc, float v) {
    out[(size_t)(tM + gr) * EE + tN + gc] = fmaxf(v + lb[tN + gc], 0.f);
  });
}

// ---------------- launch ----------------
extern "C" void kernel_launch(void* const* d_in, const int* in_sizes, int n_in,
                              void* d_out, int out_size, void* d_ws, size_t ws_size,
                              hipStream_t stream) {
  (void)in_sizes; (void)n_in; (void)out_size;
  const float* x  = (const float*)d_in[0];
  const float* nw = (const float*)d_in[1];
  const float* nb = (const float*)d_in[2];
  const float* qw = (const float*)d_in[3];
  const float* lw = (const float*)d_in[4];
  const float* lb = (const float*)d_in[5];
  float* out = (float*)d_out;
  char* ws = (char*)d_ws;

  size_t off = 0;
  auto alloc = [&](size_t bytes) { size_t o = off; off += (bytes + 255) & ~(size_t)255; return o; };
  const size_t o_psum = alloc(16 * 128 * 4);
  const size_t o_psq  = alloc(16 * 128 * 4);
  const size_t o_st   = alloc(16 * 2 * 4);
  const size_t o_qwT  = alloc((size_t)768 * 768 * 2);
  const size_t o_lwB  = alloc((size_t)768 * 256 * 2);
  const size_t o_qkv  = alloc((size_t)MM * EE * 2);
  const size_t o_kT   = alloc((size_t)BB * HH * PP * 2);
  const size_t o_vT   = alloc((size_t)BB * HH * PP * 2);
  const size_t o_Wt   = alloc((size_t)BB * HH * HH * 2);
  const size_t need_base = off;
  const size_t region = (size_t)MM * EE * 2;  // xn (50.3MB) >= wt_part (33.6MB)

  // xn and wt_part have disjoint lifetimes -> share one region; spill to d_out
  // (100.7MB, dead until the final GEMM) if ws is too small.
  char* big = (ws_size >= need_base + region) ? (ws + need_base) : (char*)d_out;
  static bool printed = false;
  if (!printed) {
    fprintf(stderr, "[vit] ws_size=%zu need=%zu big_in_out=%d\n",
            ws_size, need_base + region, big == (char*)d_out);
    printed = true;
  }

  float* psum = (float*)(ws + o_psum);
  float* psq  = (float*)(ws + o_psq);
  float* st   = (float*)(ws + o_st);
  u16* qwT    = (u16*)(ws + o_qwT);
  u16* lwB    = (u16*)(ws + o_lwB);
  u16* qkv    = (u16*)(ws + o_qkv);
  u16* kT     = (u16*)(ws + o_kT);
  u16* vT     = (u16*)(ws + o_vT);
  u16* Wt     = (u16*)(ws + o_Wt);
  u16* o_buf  = (u16*)(ws + o_kT);  // reuse kT region (dead after k_gemm_wt)
  u16* xn     = (u16*)big;
  float* part = (float*)big;

  k_reduce1<<<dim3(128, 16), 256, 0, stream>>>(x, psum, psq);
  k_reduce2<<<16, 128, 0, stream>>>(psum, psq, st);
  k_ln<<<2048, 256, 0, stream>>>(x, nw, nb, st, xn);
  k_transpose_w<<<dim3(24, 24), dim3(32, 8), 0, stream>>>(qw, qwT);
  k_cast<<<192, 256, 0, stream>>>(lw, lwB, 768 * 256 / 4);
  k_gemm_qkv<<<dim3(6, 256), 256, 0, stream>>>(xn, qwT, qkv);
  k_transpose_kv<<<dim3(64, 8, 32), dim3(32, 8), 0, stream>>>(qkv, kT, vT);
  k_gemm_wt<<<dim3(2, 2, 128), 256, 0, stream>>>(vT, kT, part);
  k_reduce_wt<<<4096, 256, 0, stream>>>(part, Wt);
  k_gemm_o<<<dim3(2, 16, 16), 256, 0, stream>>>(qkv, Wt, o_buf);
  k_gemm_lin<<<dim3(6, 256), 256, 0, stream>>>(o_buf, lwB, lb, out);
}

// Round 4
// 329.730 us; speedup vs baseline: 1.0753x; 1.0753x over previous
//
#include <hip/hip_runtime.h>
#include <cstdint>

typedef unsigned short u16;
typedef __bf16 bf16x8 __attribute__((ext_vector_type(8)));
typedef float floatx4 __attribute__((ext_vector_type(4)));

// ---------------- constants ----------------
#define BB 16
#define PP 2048
#define EE 768
#define HH 256
#define PE (PP * EE)          // 1572864
#define MM (BB * PP)          // 32768

__device__ __forceinline__ u16 f2bf(float f) {
  union { float f; uint32_t u; } v; v.f = f;
  return (u16)((v.u + 0x7fffu + ((v.u >> 16) & 1u)) >> 16);
}

__device__ __forceinline__ void gload16(const void* g, void* l) {
  typedef __attribute__((address_space(1))) const void GV;
  typedef __attribute__((address_space(3))) void LV;
  __builtin_amdgcn_global_load_lds((GV*)g, (LV*)l, 16, 0, 0);
}

// bijective XCD swizzle (nwg % 8 == 0): XCD c handles contiguous logical chunk
__device__ __forceinline__ int xcd_remap(int orig, int nwg) {
  return (orig & 7) * (nwg >> 3) + (orig >> 3);
}

// ---- 128x128-tile TN GEMM core: A[M][K] rowmajor(lda), B[N][K] rowmajor(ldb),
// BK=64, 256 threads = 4 waves (2x2), each wave 64x64 = 4x4 frags of 16x16x32.
__device__ __forceinline__ void zero_acc(floatx4 acc[4][4]) {
  const floatx4 z = {0.f, 0.f, 0.f, 0.f};
#pragma unroll
  for (int i = 0; i < 4; ++i)
#pragma unroll
    for (int j = 0; j < 4; ++j) acc[i][j] = z;
}

__device__ __forceinline__ void gemm_core(const u16* A, int lda, const u16* B, int ldb,
                                          int kIters, u16* As, u16* Bs,
                                          floatx4 acc[4][4]) {
  const int tid  = threadIdx.x;
  const int lane = tid & 63;
  const int wr   = (tid >> 7) & 1;
  const int wc   = (tid >> 6) & 1;
  const int srow = tid >> 3;           // 0..31
  const int scol = (tid & 7) << 3;     // 0..56
  const int mrow = lane & 15;
  const int kgrp = (lane >> 4) << 3;   // 0,8,16,24
  for (int kk = 0; kk < kIters; ++kk) {
    const u16* Ak = A + kk * 64;
    const u16* Bk = B + kk * 64;
    __syncthreads();  // previous compute done before LDS overwrite
#pragma unroll
    for (int r = 0; r < 4; ++r) {
      gload16(Ak + (size_t)(r * 32 + srow) * lda + scol, (char*)As + r * 4096 + tid * 16);
      gload16(Bk + (size_t)(r * 32 + srow) * ldb + scol, (char*)Bs + r * 4096 + tid * 16);
    }
    __syncthreads();  // compiler drains vmcnt before barrier
#pragma unroll
    for (int kp = 0; kp < 2; ++kp) {
      const int ko = kp * 32 + kgrp;
      bf16x8 af[4], bq[4];
#pragma unroll
      for (int i = 0; i < 4; ++i) {
        af[i] = *(const bf16x8*)(As + (wr * 64 + i * 16 + mrow) * 64 + ko);
        bq[i] = *(const bf16x8*)(Bs + (wc * 64 + i * 16 + mrow) * 64 + ko);
      }
#pragma unroll
      for (int i = 0; i < 4; ++i)
#pragma unroll
        for (int j = 0; j < 4; ++j)
          acc[i][j] = __builtin_amdgcn_mfma_f32_16x16x32_bf16(af[i], bq[j], acc[i][j], 0, 0, 0);
    }
  }
}

template <typename F>
__device__ __forceinline__ void epilogue(floatx4 acc[4][4], F f) {
  const int lane = threadIdx.x & 63;
  const int wr = (threadIdx.x >> 7) & 1, wc = (threadIdx.x >> 6) & 1;
  const int r0 = (lane >> 4) * 4, c0 = lane & 15;
#pragma unroll
  for (int i = 0; i < 4; ++i)
#pragma unroll
    for (int j = 0; j < 4; ++j)
#pragma unroll
      for (int r = 0; r < 4; ++r)
        f(wr * 64 + i * 16 + r0 + r, wc * 64 + j * 16 + c0, acc[i][j][r]);
}

// ---------------- LayerNorm ----------------
__global__ __launch_bounds__(256) void k_reduce1(const float* __restrict__ x,
                                                 float* __restrict__ psum,
                                                 float* __restrict__ psq) {
  const int b = blockIdx.y, blk = blockIdx.x, tid = threadIdx.x;
  const float4* xb = (const float4*)(x + (size_t)b * PE + (size_t)blk * 12288);
  float s = 0.f, q = 0.f;
#pragma unroll
  for (int i = 0; i < 12; ++i) {
    float4 v = xb[tid + i * 256];
    s += v.x + v.y + v.z + v.w;
    q += v.x * v.x + v.y * v.y + v.z * v.z + v.w * v.w;
  }
  for (int off = 32; off > 0; off >>= 1) { s += __shfl_down(s, off); q += __shfl_down(q, off); }
  __shared__ float ls[4], lq[4];
  if ((tid & 63) == 0) { ls[tid >> 6] = s; lq[tid >> 6] = q; }
  __syncthreads();
  if (tid == 0) {
    psum[b * 128 + blk] = ls[0] + ls[1] + ls[2] + ls[3];
    psq [b * 128 + blk] = lq[0] + lq[1] + lq[2] + lq[3];
  }
}

__global__ void k_reduce2(const float* __restrict__ psum, const float* __restrict__ psq,
                          float* __restrict__ stats) {
  const int b = blockIdx.x, tid = threadIdx.x;  // 128 threads
  float s = psum[b * 128 + tid], q = psq[b * 128 + tid];
  for (int off = 32; off > 0; off >>= 1) { s += __shfl_down(s, off); q += __shfl_down(q, off); }
  __shared__ float ls[2], lq[2];
  if ((tid & 63) == 0) { ls[tid >> 6] = s; lq[tid >> 6] = q; }
  __syncthreads();
  if (tid == 0) {
    float S = ls[0] + ls[1], Q = lq[0] + lq[1];
    const float invN = 1.f / (float)PE;
    float mean = S * invN;
    float var = Q * invN - mean * mean;
    stats[b * 2] = mean;
    stats[b * 2 + 1] = rsqrtf(var + 1e-5f);
  }
}

__global__ __launch_bounds__(256) void k_ln(const float* __restrict__ x,
                                            const float* __restrict__ w,
                                            const float* __restrict__ bia,
                                            const float* __restrict__ stats,
                                            u16* __restrict__ xn) {
  const float4* x4 = (const float4*)x;
  const float4* w4 = (const float4*)w;
  const float4* b4 = (const float4*)bia;
  for (int vi = blockIdx.x * 256 + threadIdx.x; vi < (PE / 4) * BB; vi += gridDim.x * 256) {
    int bidx = vi / (PE / 4);
    int wi = vi - bidx * (PE / 4);
    float4 xv = x4[vi], wv = w4[wi], bv = b4[wi];
    float mean = stats[bidx * 2], rstd = stats[bidx * 2 + 1];
    ushort4 o;
    o.x = f2bf((xv.x - mean) * rstd * wv.x + bv.x);
    o.y = f2bf((xv.y - mean) * rstd * wv.y + bv.y);
    o.z = f2bf((xv.z - mean) * rstd * wv.z + bv.z);
    o.w = f2bf((xv.w - mean) * rstd * wv.w + bv.w);
    ((ushort4*)xn)[vi] = o;
  }
}

// ---------------- weight prep ----------------
// qkv_w [E][3H] fp32 -> wT [n][e] bf16 (transposed)
__global__ void k_transpose_w(const float* __restrict__ src, u16* __restrict__ dst) {
  __shared__ float t[32][33];
  const int e0 = blockIdx.x * 32, n0 = blockIdx.y * 32;
  const int tx = threadIdx.x, ty = threadIdx.y;  // 32x8
#pragma unroll
  for (int j = 0; j < 4; ++j)
    t[ty + j * 8][tx] = src[(size_t)(e0 + ty + j * 8) * 768 + n0 + tx];
  __syncthreads();
#pragma unroll
  for (int j = 0; j < 4; ++j)
    dst[(size_t)(n0 + ty + j * 8) * 768 + e0 + tx] = f2bf(t[tx][ty + j * 8]);
}

__global__ void k_cast(const float* __restrict__ src, u16* __restrict__ dst, int n4) {
  int i = blockIdx.x * 256 + threadIdx.x;
  if (i < n4) {
    float4 v = ((const float4*)src)[i];
    ushort4 o;
    o.x = f2bf(v.x); o.y = f2bf(v.y); o.z = f2bf(v.z); o.w = f2bf(v.w);
    ((ushort4*)dst)[i] = o;
  }
}

// ---------------- QKV GEMM with fused K/V transpose epilogue ----------------
// x-tiles 0,1 -> q_buf[p][d] (d = x*128+gc). x-tiles 2..5 -> kT/vT[b][d][p] via
// LDS transpose (64-col halves, padded stride 144 u16 = 288B, 16B aligned).
__global__ __launch_bounds__(256) void k_gemm_qkv(const u16* __restrict__ xn,
                                                  const u16* __restrict__ wT,
                                                  u16* __restrict__ q_buf,
                                                  u16* __restrict__ kT,
                                                  u16* __restrict__ vT) {
  __shared__ __align__(16) u16 sbuf[128 * 64 * 2];  // As | Bs, reused for transpose
  u16* As = sbuf;
  u16* Bs = sbuf + 128 * 64;
  floatx4 acc[4][4];
  zero_acc(acc);
  const int t = xcd_remap(blockIdx.x, 1536);
  const int xt = t % 6, yt = t / 6;          // yt in [0,256): b = yt>>4, ptile = yt&15
  const int tM = yt * 128, tN = xt * 128;
  gemm_core(xn + (size_t)tM * EE, EE, wT + (size_t)tN * EE, EE, 12, As, Bs, acc);

  if (xt < 2) {
    epilogue(acc, [&](int gr, int gc, float v) {
      q_buf[(size_t)(tM + gr) * HH + xt * 128 + gc] = f2bf(v);
    });
  } else {
    const int b = yt >> 4;
    const int p_base = (yt & 15) * 128;      // p index local to batch
    u16* dst = ((xt < 4) ? kT : vT) + (size_t)b * (HH * PP);
    const int dbase = (xt - ((xt < 4) ? 2 : 4)) * 128;
    u16 (*tt)[144] = (u16(*)[144])sbuf;  // 64 x 144 (18432 B <= 32768)
    const int tid = threadIdx.x;
    const int lane = tid & 63;
    const int wr = (tid >> 7) & 1, wc = (tid >> 6) & 1;
    const int r0 = (lane >> 4) * 4, c0 = lane & 15;
#pragma unroll
    for (int h = 0; h < 2; ++h) {
      __syncthreads();  // LDS free (gemm reads done / prior readout done)
      if (wc == h) {
#pragma unroll
        for (int i = 0; i < 4; ++i)
#pragma unroll
          for (int j = 0; j < 4; ++j)
#pragma unroll
            for (int r = 0; r < 4; ++r)
              tt[j * 16 + c0][wr * 64 + i * 16 + r0 + r] = f2bf(acc[i][j][r]);
      }
      __syncthreads();
#pragma unroll
      for (int pass = 0; pass < 4; ++pass) {
        const int row = pass * 16 + (tid >> 4);   // 0..63 (local d within half)
        const int p8 = (tid & 15) * 8;            // 0..120 (local p, x8 u16)
        const int d = dbase + h * 64 + row;
        uint4 vdat = *(const uint4*)&tt[row][p8];
        *(uint4*)&dst[(size_t)d * PP + p_base + p8] = vdat;
      }
    }
  }
}

// G[d1][d2] = sum_p k[p][d1] v[p][d2]  (split-K=8 fp32 partials)
__global__ __launch_bounds__(256) void k_gemm_w2(const u16* __restrict__ kT,
                                                 const u16* __restrict__ vT,
                                                 float* __restrict__ part) {
  __shared__ __align__(16) u16 As[128 * 64], Bs[128 * 64];
  floatx4 acc[4][4];
  zero_acc(acc);
  const int t = xcd_remap(blockIdx.x, 512);
  const int xt = t & 1, yt = (t >> 1) & 1, z = t >> 2;  // z = b*8+s
  const int b = z >> 3, s = z & 7;
  const int tM = yt * 128, tN = xt * 128;
  const u16* A = kT + (size_t)b * (HH * PP) + (size_t)tM * PP + s * 256;
  const u16* B = vT + (size_t)b * (HH * PP) + (size_t)tN * PP + s * 256;
  gemm_core(A, PP, B, PP, 4, As, Bs, acc);
  float* P = part + (size_t)z * 65536;
  epilogue(acc, [&](int gr, int gc, float v) {
    P[(size_t)(tM + gr) * 256 + tN + gc] = v;
  });
}

__global__ void k_reduce_w2(const float* __restrict__ part, u16* __restrict__ W2) {
  const int idx = blockIdx.x * 256 + threadIdx.x;  // < 16*256*256
  const int b = idx >> 16, i = idx & 65535;
  const float* p = part + ((size_t)b << 19) + i;
  float s = 0.f;
#pragma unroll
  for (int t = 0; t < 8; ++t) s += p[(size_t)t << 16];
  W2[idx] = f2bf(s);
}

// M2T[e][d1] = sum_d2 lw[e][d2] * G[d1][d2]   (per batch)
__global__ __launch_bounds__(256) void k_gemm_m2(const u16* __restrict__ lwB,
                                                 const u16* __restrict__ W2,
                                                 u16* __restrict__ M2T) {
  __shared__ __align__(16) u16 As[128 * 64], Bs[128 * 64];
  floatx4 acc[4][4];
  zero_acc(acc);
  const int t = xcd_remap(blockIdx.x, 192);
  const int xt = t & 1, yt = (t >> 1) % 6, b = t / 12;
  const int tM = yt * 128, tN = xt * 128;
  const u16* A = lwB + (size_t)tM * HH;
  const u16* B = W2 + (size_t)b * 65536 + (size_t)tN * HH;
  gemm_core(A, HH, B, HH, 4, As, Bs, acc);
  u16* Mb = M2T + (size_t)b * (EE * HH);
  epilogue(acc, [&](int gr, int gc, float v) {
    Mb[(size_t)(tM + gr) * HH + tN + gc] = f2bf(v);
  });
}

// out[p][e] = relu(sum_d1 q[p][d1] * M2T[e][d1] + lb[e])
__global__ __launch_bounds__(256) void k_gemm_out(const u16* __restrict__ q_buf,
                                                  const u16* __restrict__ M2T,
                                                  const float* __restrict__ lb,
                                                  float* __restrict__ out) {
  __shared__ __align__(16) u16 As[128 * 64], Bs[128 * 64];
  floatx4 acc[4][4];
  zero_acc(acc);
  const int t = xcd_remap(blockIdx.x, 1536);
  const int xt = t % 6, yt = (t / 6) % 16, b = t / 96;
  const int tM = yt * 128, tN = xt * 128;
  const u16* A = q_buf + (size_t)b * (PP * HH) + (size_t)tM * HH;
  const u16* B = M2T + (size_t)b * (EE * HH) + (size_t)tN * HH;
  gemm_core(A, HH, B, HH, 4, As, Bs, acc);
  float* ob = out + (size_t)b * PE;
  epilogue(acc, [&](int gr, int gc, float v) {
    ob[(size_t)(tM + gr) * EE + tN + gc] = fmaxf(v + lb[tN + gc], 0.f);
  });
}

// ---------------- launch ----------------
extern "C" void kernel_launch(void* const* d_in, const int* in_sizes, int n_in,
                              void* d_out, int out_size, void* d_ws, size_t ws_size,
                              hipStream_t stream) {
  (void)in_sizes; (void)n_in; (void)out_size;
  const float* x  = (const float*)d_in[0];
  const float* nw = (const float*)d_in[1];
  const float* nb = (const float*)d_in[2];
  const float* qw = (const float*)d_in[3];
  const float* lw = (const float*)d_in[4];
  const float* lb = (const float*)d_in[5];
  float* out = (float*)d_out;
  char* ws = (char*)d_ws;

  size_t off = 0;
  auto alloc = [&](size_t bytes) { size_t o = off; off += (bytes + 255) & ~(size_t)255; return o; };
  const size_t o_psum = alloc(16 * 128 * 4);
  const size_t o_psq  = alloc(16 * 128 * 4);
  const size_t o_st   = alloc(16 * 2 * 4);
  const size_t o_qwT  = alloc((size_t)768 * 768 * 2);
  const size_t o_lwB  = alloc((size_t)768 * 256 * 2);
  const size_t o_q    = alloc((size_t)MM * HH * 2);        // 16.8 MB
  const size_t o_kT   = alloc((size_t)BB * HH * PP * 2);   // 16.8 MB
  const size_t o_vT   = alloc((size_t)BB * HH * PP * 2);   // 16.8 MB
  const size_t o_W2   = alloc((size_t)BB * HH * HH * 2);   // 2.1 MB
  const size_t o_M2T  = alloc((size_t)BB * EE * HH * 2);   // 6.3 MB
  const size_t need_base = off;
  const size_t region = (size_t)MM * EE * 2;  // xn (50.3MB) >= part (33.6MB)

  // xn and part have disjoint lifetimes -> share one region; spill to d_out
  // (100.7MB fp32, dead until k_gemm_out) if ws is too small.
  char* big = (ws_size >= need_base + region) ? (ws + need_base) : (char*)d_out;

  float* psum = (float*)(ws + o_psum);
  float* psq  = (float*)(ws + o_psq);
  float* st   = (float*)(ws + o_st);
  u16* qwT    = (u16*)(ws + o_qwT);
  u16* lwB    = (u16*)(ws + o_lwB);
  u16* q_buf  = (u16*)(ws + o_q);
  u16* kT     = (u16*)(ws + o_kT);
  u16* vT     = (u16*)(ws + o_vT);
  u16* W2     = (u16*)(ws + o_W2);
  u16* M2T    = (u16*)(ws + o_M2T);
  u16* xn     = (u16*)big;
  float* part = (float*)big;

  k_reduce1<<<dim3(128, 16), 256, 0, stream>>>(x, psum, psq);
  k_reduce2<<<16, 128, 0, stream>>>(psum, psq, st);
  k_ln<<<2048, 256, 0, stream>>>(x, nw, nb, st, xn);
  k_transpose_w<<<dim3(24, 24), dim3(32, 8), 0, stream>>>(qw, qwT);
  k_cast<<<192, 256, 0, stream>>>(lw, lwB, 768 * 256 / 4);
  k_gemm_qkv<<<1536, 256, 0, stream>>>(xn, qwT, q_buf, kT, vT);
  k_gemm_w2<<<512, 256, 0, stream>>>(kT, vT, part);
  k_reduce_w2<<<4096, 256, 0, stream>>>(part, W2);
  k_gemm_m2<<<192, 256, 0, stream>>>(lwB, W2, M2T);
  k_gemm_out<<<1536, 256, 0, stream>>>(q_buf, M2T, lb, out);
}

// Round 5
// 328.117 us; speedup vs baseline: 1.0806x; 1.0049x over previous
//
#include <hip/hip_runtime.h>
#include <cstdint>

typedef unsigned short u16;
typedef __bf16 bf16x8 __attribute__((ext_vector_type(8)));
typedef float floatx4 __attribute__((ext_vector_type(4)));

// ---------------- constants ----------------
#define BB 16
#define PP 2048
#define EE 768
#define HH 256
#define PE (PP * EE)          // 1572864
#define MM (BB * PP)          // 32768

__device__ __forceinline__ u16 f2bf(float f) {
  union { float f; uint32_t u; } v; v.f = f;
  return (u16)((v.u + 0x7fffu + ((v.u >> 16) & 1u)) >> 16);
}

__device__ __forceinline__ void gload16(const void* g, void* l) {
  typedef __attribute__((address_space(1))) const void GV;
  typedef __attribute__((address_space(3))) void LV;
  __builtin_amdgcn_global_load_lds((GV*)g, (LV*)l, 16, 0, 0);
}

// bijective XCD swizzle (nwg % 8 == 0): XCD c handles contiguous logical chunk
__device__ __forceinline__ int xcd_remap(int orig, int nwg) {
  return (orig & 7) * (nwg >> 3) + (orig >> 3);
}

// ---- 128x128-tile TN GEMM core (m97 structure) — used by the small GEMMs ----
__device__ __forceinline__ void zero_acc4(floatx4 acc[4][4]) {
  const floatx4 z = {0.f, 0.f, 0.f, 0.f};
#pragma unroll
  for (int i = 0; i < 4; ++i)
#pragma unroll
    for (int j = 0; j < 4; ++j) acc[i][j] = z;
}

__device__ __forceinline__ void gemm_core(const u16* A, int lda, const u16* B, int ldb,
                                          int kIters, u16* As, u16* Bs,
                                          floatx4 acc[4][4]) {
  const int tid  = threadIdx.x;
  const int lane = tid & 63;
  const int wr   = (tid >> 7) & 1;
  const int wc   = (tid >> 6) & 1;
  const int srow = tid >> 3;           // 0..31
  const int scol = (tid & 7) << 3;     // 0..56
  const int mrow = lane & 15;
  const int kgrp = (lane >> 4) << 3;   // 0,8,16,24
  for (int kk = 0; kk < kIters; ++kk) {
    const u16* Ak = A + kk * 64;
    const u16* Bk = B + kk * 64;
    __syncthreads();
#pragma unroll
    for (int r = 0; r < 4; ++r) {
      gload16(Ak + (size_t)(r * 32 + srow) * lda + scol, (char*)As + r * 4096 + tid * 16);
      gload16(Bk + (size_t)(r * 32 + srow) * ldb + scol, (char*)Bs + r * 4096 + tid * 16);
    }
    __syncthreads();
#pragma unroll
    for (int kp = 0; kp < 2; ++kp) {
      const int ko = kp * 32 + kgrp;
      bf16x8 af[4], bq[4];
#pragma unroll
      for (int i = 0; i < 4; ++i) {
        af[i] = *(const bf16x8*)(As + (wr * 64 + i * 16 + mrow) * 64 + ko);
        bq[i] = *(const bf16x8*)(Bs + (wc * 64 + i * 16 + mrow) * 64 + ko);
      }
#pragma unroll
      for (int i = 0; i < 4; ++i)
#pragma unroll
        for (int j = 0; j < 4; ++j)
          acc[i][j] = __builtin_amdgcn_mfma_f32_16x16x32_bf16(af[i], bq[j], acc[i][j], 0, 0, 0);
    }
  }
}

template <typename F>
__device__ __forceinline__ void epilogue4(floatx4 acc[4][4], F f) {
  const int lane = threadIdx.x & 63;
  const int wr = (threadIdx.x >> 7) & 1, wc = (threadIdx.x >> 6) & 1;
  const int r0 = (lane >> 4) * 4, c0 = lane & 15;
#pragma unroll
  for (int i = 0; i < 4; ++i)
#pragma unroll
    for (int j = 0; j < 4; ++j)
#pragma unroll
      for (int r = 0; r < 4; ++r)
        f(wr * 64 + i * 16 + r0 + r, wc * 64 + j * 16 + c0, acc[i][j][r]);
}

// ================= 256x256 8-phase GEMM (QKV) =================
// 512 thr = 8 waves (2 Mx4 N); per-wave 128x64 out = acc[8][4]; BK=64.
// LDS 128KB: A[2buf][2half][128][64] | B[2buf][2half][128][64], bf16.
// T2 swizzle: 16B chunk c stored at c ^ (row&7) (inverse-swz source, swz read).
// Schedule/iter (2 K-steps): ph0 stage8(buf1<-2t+1); ph0-3 compute buf0;
// vmcnt(0) at ph3-end; ph4 stage8(buf0<-2t+2); ph4-7 compute buf1; vmcnt(0)
// at ph7-end. Drains sit 3 compute-phases after issue -> loads stay in
// flight across barriers (T3/T4); raw s_barrier pairs per phase; T5 setprio.

__device__ __forceinline__ void stage8(u16* sm, int bf, const u16* A, const u16* Bw,
                                       int ks, int tid) {
  const int colc = (((tid & 7) ^ ((tid >> 3) & 7)) << 3) + ks * 64;
  const int rw = tid >> 3;  // 0..63
#pragma unroll
  for (int h = 0; h < 2; ++h)
#pragma unroll
    for (int L = 0; L < 2; ++L)
      gload16(A + (size_t)(h * 128 + L * 64 + rw) * EE + colc,
              (char*)sm + (size_t)(bf * 16384 + h * 8192 + L * 4096 + tid * 8) * 2);
#pragma unroll
  for (int h = 0; h < 2; ++h)
#pragma unroll
    for (int L = 0; L < 2; ++L)
      gload16(Bw + (size_t)(h * 128 + L * 64 + rw) * EE + colc,
              (char*)sm + (size_t)(32768 + bf * 16384 + h * 8192 + L * 4096 + tid * 8) * 2);
}

template <int IH, int JH>
__device__ __forceinline__ void phase_mfma(const u16* sm, int bf, int wr, int wcn,
                                           int lane, floatx4 acc[8][4]) {
  const int m = lane & 15, hi = lane >> 4, mk = m & 7;
  bf16x8 a[4][2], b[2][2];
#pragma unroll
  for (int ii = 0; ii < 4; ++ii) {
    const int r = (IH * 4 + ii) * 16 + m;
#pragma unroll
    for (int kp = 0; kp < 2; ++kp)
      a[ii][kp] = *(const bf16x8*)(sm + bf * 16384 + wr * 8192 + r * 64 +
                                   (((kp * 4 + hi) ^ mk) << 3));
  }
#pragma unroll
  for (int jj = 0; jj < 2; ++jj) {
    const int r = (wcn & 1) * 64 + (JH * 2 + jj) * 16 + m;
#pragma unroll
    for (int kp = 0; kp < 2; ++kp)
      b[jj][kp] = *(const bf16x8*)(sm + 32768 + bf * 16384 + (wcn >> 1) * 8192 + r * 64 +
                                   (((kp * 4 + hi) ^ mk) << 3));
  }
  __builtin_amdgcn_s_barrier();  // barrier#1: phase-lock (no counter drain)
  __builtin_amdgcn_s_setprio(1);
#pragma unroll
  for (int ii = 0; ii < 4; ++ii)
#pragma unroll
    for (int jj = 0; jj < 2; ++jj)
#pragma unroll
      for (int kp = 0; kp < 2; ++kp)
        acc[IH * 4 + ii][JH * 2 + jj] = __builtin_amdgcn_mfma_f32_16x16x32_bf16(
            a[ii][kp], b[jj][kp], acc[IH * 4 + ii][JH * 2 + jj], 0, 0, 0);
  __builtin_amdgcn_s_setprio(0);
}

__global__ __launch_bounds__(512, 2) void k_gemm_qkv8(const u16* __restrict__ xn,
                                                      const u16* __restrict__ wT,
                                                      u16* __restrict__ q_buf,
                                                      u16* __restrict__ kT,
                                                      u16* __restrict__ vT) {
  __shared__ __align__(16) u16 sm[65536];  // 128 KiB
  floatx4 acc[8][4];
  const floatx4 z = {0.f, 0.f, 0.f, 0.f};
#pragma unroll
  for (int i = 0; i < 8; ++i)
#pragma unroll
    for (int j = 0; j < 4; ++j) acc[i][j] = z;

  const int t = xcd_remap(blockIdx.x, 384);
  const int xt = t % 3;                 // 0=q, 1=k, 2=v (tile N = 256 = one of q/k/v)
  const int yt = t / 3;                 // 0..127
  const int tM = yt * 256, tN = xt * 256;
  const u16* A  = xn + (size_t)tM * EE;
  const u16* Bw = wT + (size_t)tN * EE;
  const int tid = threadIdx.x, lane = tid & 63, wid = tid >> 6;
  const int wr = wid >> 2, wcn = wid & 3;

  stage8(sm, 0, A, Bw, 0, tid);         // prologue: buf0 <- step 0
  asm volatile("s_waitcnt vmcnt(0)" ::: "memory");
  __builtin_amdgcn_sched_barrier(0);
  __builtin_amdgcn_s_barrier();

  const int NT2 = (EE / 64) / 2;        // 6 iters, 2 K-steps each
  for (int it = 0; it < NT2; ++it) {
    stage8(sm, 1, A, Bw, 2 * it + 1, tid);                 // ph0 burst -> buf1
    phase_mfma<0, 0>(sm, 0, wr, wcn, lane, acc);
    __builtin_amdgcn_s_barrier();
    phase_mfma<0, 1>(sm, 0, wr, wcn, lane, acc);
    __builtin_amdgcn_s_barrier();
    phase_mfma<1, 0>(sm, 0, wr, wcn, lane, acc);
    __builtin_amdgcn_s_barrier();
    phase_mfma<1, 1>(sm, 0, wr, wcn, lane, acc);
    asm volatile("s_waitcnt vmcnt(0)" ::: "memory");        // buf1 ready (3-phase gap)
    __builtin_amdgcn_sched_barrier(0);
    __builtin_amdgcn_s_barrier();
    if (2 * it + 2 < EE / 64) stage8(sm, 0, A, Bw, 2 * it + 2, tid);  // ph4 burst -> buf0
    phase_mfma<0, 0>(sm, 1, wr, wcn, lane, acc);
    __builtin_amdgcn_s_barrier();
    phase_mfma<0, 1>(sm, 1, wr, wcn, lane, acc);
    __builtin_amdgcn_s_barrier();
    phase_mfma<1, 0>(sm, 1, wr, wcn, lane, acc);
    __builtin_amdgcn_s_barrier();
    phase_mfma<1, 1>(sm, 1, wr, wcn, lane, acc);
    asm volatile("s_waitcnt vmcnt(0)" ::: "memory");        // buf0 ready for next iter
    __builtin_amdgcn_sched_barrier(0);
    __builtin_amdgcn_s_barrier();
  }

  // -------- epilogue (LDS free; per-wave private 16KB scratch) --------
  const int c0 = lane & 15, r0v = (lane >> 4) * 4;
  if (xt == 0) {
    // q: straight [p][d] write
#pragma unroll
    for (int i = 0; i < 8; ++i)
#pragma unroll
      for (int j = 0; j < 4; ++j)
#pragma unroll
        for (int r = 0; r < 4; ++r)
          q_buf[(size_t)(tM + wr * 128 + i * 16 + r0v + r) * HH + wcn * 64 + j * 16 + c0] =
              f2bf(acc[i][j][r]);
  } else {
    // k/v: per-wave LDS transpose -> [b][d][p], coalesced 16B stores
    u16* dst = (xt == 1 ? kT : vT);
    const int b = yt >> 3, p0 = (yt & 7) * 256;
    u16* db = dst + (size_t)b * (HH * PP);
    u16* tt = sm + wid * 8192;          // 16KB per wave
#pragma unroll
    for (int jh = 0; jh < 2; ++jh) {
      // write [32 d][136 p] (pad 136 breaks bank aliasing)
#pragma unroll
      for (int jj = 0; jj < 2; ++jj)
#pragma unroll
        for (int i = 0; i < 8; ++i) {
          ushort4 w4;
          w4.x = f2bf(acc[i][jh * 2 + jj][0]);
          w4.y = f2bf(acc[i][jh * 2 + jj][1]);
          w4.z = f2bf(acc[i][jh * 2 + jj][2]);
          w4.w = f2bf(acc[i][jh * 2 + jj][3]);
          *(ushort4*)&tt[(jj * 16 + c0) * 136 + i * 16 + r0v] = w4;
        }
      // read rows (d) x 128 p, store coalesced (wave-private: no barrier)
#pragma unroll
      for (int pass = 0; pass < 8; ++pass) {
        const int dl = pass * 4 + (lane >> 4), p8 = (lane & 15) * 8;
        uint4 vdat = *(const uint4*)&tt[dl * 136 + p8];
        const int d = wcn * 64 + jh * 32 + dl;
        *(uint4*)&db[(size_t)d * PP + p0 + wr * 128 + p8] = vdat;
      }
    }
  }
}

// ---------------- LayerNorm ----------------
__global__ __launch_bounds__(256) void k_reduce1(const float* __restrict__ x,
                                                 float* __restrict__ psum,
                                                 float* __restrict__ psq) {
  const int b = blockIdx.y, blk = blockIdx.x, tid = threadIdx.x;
  const float4* xb = (const float4*)(x + (size_t)b * PE + (size_t)blk * 12288);
  float s = 0.f, q = 0.f;
#pragma unroll
  for (int i = 0; i < 12; ++i) {
    float4 v = xb[tid + i * 256];
    s += v.x + v.y + v.z + v.w;
    q += v.x * v.x + v.y * v.y + v.z * v.z + v.w * v.w;
  }
  for (int off = 32; off > 0; off >>= 1) { s += __shfl_down(s, off); q += __shfl_down(q, off); }
  __shared__ float ls[4], lq[4];
  if ((tid & 63) == 0) { ls[tid >> 6] = s; lq[tid >> 6] = q; }
  __syncthreads();
  if (tid == 0) {
    psum[b * 128 + blk] = ls[0] + ls[1] + ls[2] + ls[3];
    psq [b * 128 + blk] = lq[0] + lq[1] + lq[2] + lq[3];
  }
}

__global__ void k_reduce2(const float* __restrict__ psum, const float* __restrict__ psq,
                          float* __restrict__ stats) {
  const int b = blockIdx.x, tid = threadIdx.x;  // 128 threads
  float s = psum[b * 128 + tid], q = psq[b * 128 + tid];
  for (int off = 32; off > 0; off >>= 1) { s += __shfl_down(s, off); q += __shfl_down(q, off); }
  __shared__ float ls[2], lq[2];
  if ((tid & 63) == 0) { ls[tid >> 6] = s; lq[tid >> 6] = q; }
  __syncthreads();
  if (tid == 0) {
    float S = ls[0] + ls[1], Q = lq[0] + lq[1];
    const float invN = 1.f / (float)PE;
    float mean = S * invN;
    float var = Q * invN - mean * mean;
    stats[b * 2] = mean;
    stats[b * 2 + 1] = rsqrtf(var + 1e-5f);
  }
}

__global__ __launch_bounds__(256) void k_ln(const float* __restrict__ x,
                                            const float* __restrict__ w,
                                            const float* __restrict__ bia,
                                            const float* __restrict__ stats,
                                            u16* __restrict__ xn) {
  const float4* x4 = (const float4*)x;
  const float4* w4 = (const float4*)w;
  const float4* b4 = (const float4*)bia;
  for (int vi = blockIdx.x * 256 + threadIdx.x; vi < (PE / 4) * BB; vi += gridDim.x * 256) {
    int bidx = vi / (PE / 4);
    int wi = vi - bidx * (PE / 4);
    float4 xv = x4[vi], wv = w4[wi], bv = b4[wi];
    float mean = stats[bidx * 2], rstd = stats[bidx * 2 + 1];
    ushort4 o;
    o.x = f2bf((xv.x - mean) * rstd * wv.x + bv.x);
    o.y = f2bf((xv.y - mean) * rstd * wv.y + bv.y);
    o.z = f2bf((xv.z - mean) * rstd * wv.z + bv.z);
    o.w = f2bf((xv.w - mean) * rstd * wv.w + bv.w);
    ((ushort4*)xn)[vi] = o;
  }
}

// ---------------- weight prep ----------------
__global__ void k_transpose_w(const float* __restrict__ src, u16* __restrict__ dst) {
  __shared__ float t[32][33];
  const int e0 = blockIdx.x * 32, n0 = blockIdx.y * 32;
  const int tx = threadIdx.x, ty = threadIdx.y;  // 32x8
#pragma unroll
  for (int j = 0; j < 4; ++j)
    t[ty + j * 8][tx] = src[(size_t)(e0 + ty + j * 8) * 768 + n0 + tx];
  __syncthreads();
#pragma unroll
  for (int j = 0; j < 4; ++j)
    dst[(size_t)(n0 + ty + j * 8) * 768 + e0 + tx] = f2bf(t[tx][ty + j * 8]);
}

__global__ void k_cast(const float* __restrict__ src, u16* __restrict__ dst, int n4) {
  int i = blockIdx.x * 256 + threadIdx.x;
  if (i < n4) {
    float4 v = ((const float4*)src)[i];
    ushort4 o;
    o.x = f2bf(v.x); o.y = f2bf(v.y); o.z = f2bf(v.z); o.w = f2bf(v.w);
    ((ushort4*)dst)[i] = o;
  }
}

// G[d1][d2] = sum_p k[p][d1] v[p][d2]  (split-K=8 fp32 partials)
__global__ __launch_bounds__(256) void k_gemm_w2(const u16* __restrict__ kT,
                                                 const u16* __restrict__ vT,
                                                 float* __restrict__ part) {
  __shared__ __align__(16) u16 As[128 * 64], Bs[128 * 64];
  floatx4 acc[4][4];
  zero_acc4(acc);
  const int t = xcd_remap(blockIdx.x, 512);
  const int xt = t & 1, yt = (t >> 1) & 1, z = t >> 2;  // z = b*8+s
  const int b = z >> 3, s = z & 7;
  const int tM = yt * 128, tN = xt * 128;
  const u16* A = kT + (size_t)b * (HH * PP) + (size_t)tM * PP + s * 256;
  const u16* B = vT + (size_t)b * (HH * PP) + (size_t)tN * PP + s * 256;
  gemm_core(A, PP, B, PP, 4, As, Bs, acc);
  float* P = part + (size_t)z * 65536;
  epilogue4(acc, [&](int gr, int gc, float v) {
    P[(size_t)(tM + gr) * 256 + tN + gc] = v;
  });
}

__global__ void k_reduce_w2(const float* __restrict__ part, u16* __restrict__ W2) {
  const int idx = blockIdx.x * 256 + threadIdx.x;  // < 16*256*256
  const int b = idx >> 16, i = idx & 65535;
  const float* p = part + ((size_t)b << 19) + i;
  float s = 0.f;
#pragma unroll
  for (int t = 0; t < 8; ++t) s += p[(size_t)t << 16];
  W2[idx] = f2bf(s);
}

// M2T[e][d1] = sum_d2 lw[e][d2] * G[d1][d2]   (per batch)
__global__ __launch_bounds__(256) void k_gemm_m2(const u16* __restrict__ lwB,
                                                 const u16* __restrict__ W2,
                                                 u16* __restrict__ M2T) {
  __shared__ __align__(16) u16 As[128 * 64], Bs[128 * 64];
  floatx4 acc[4][4];
  zero_acc4(acc);
  const int t = xcd_remap(blockIdx.x, 192);
  const int xt = t & 1, yt = (t >> 1) % 6, b = t / 12;
  const int tM = yt * 128, tN = xt * 128;
  const u16* A = lwB + (size_t)tM * HH;
  const u16* B = W2 + (size_t)b * 65536 + (size_t)tN * HH;
  gemm_core(A, HH, B, HH, 4, As, Bs, acc);
  u16* Mb = M2T + (size_t)b * (EE * HH);
  epilogue4(acc, [&](int gr, int gc, float v) {
    Mb[(size_t)(tM + gr) * HH + tN + gc] = f2bf(v);
  });
}

// out[p][e] = relu(sum_d1 q[p][d1] * M2T[e][d1] + lb[e])
__global__ __launch_bounds__(256) void k_gemm_out(const u16* __restrict__ q_buf,
                                                  const u16* __restrict__ M2T,
                                                  const float* __restrict__ lb,
                                                  float* __restrict__ out) {
  __shared__ __align__(16) u16 As[128 * 64], Bs[128 * 64];
  floatx4 acc[4][4];
  zero_acc4(acc);
  const int t = xcd_remap(blockIdx.x, 1536);
  const int xt = t % 6, yt = (t / 6) % 16, b = t / 96;
  const int tM = yt * 128, tN = xt * 128;
  const u16* A = q_buf + (size_t)b * (PP * HH) + (size_t)tM * HH;
  const u16* B = M2T + (size_t)b * (EE * HH) + (size_t)tN * HH;
  gemm_core(A, HH, B, HH, 4, As, Bs, acc);
  float* ob = out + (size_t)b * PE;
  epilogue4(acc, [&](int gr, int gc, float v) {
    ob[(size_t)(tM + gr) * EE + tN + gc] = fmaxf(v + lb[tN + gc], 0.f);
  });
}

// ---------------- launch ----------------
extern "C" void kernel_launch(void* const* d_in, const int* in_sizes, int n_in,
                              void* d_out, int out_size, void* d_ws, size_t ws_size,
                              hipStream_t stream) {
  (void)in_sizes; (void)n_in; (void)out_size;
  const float* x  = (const float*)d_in[0];
  const float* nw = (const float*)d_in[1];
  const float* nb = (const float*)d_in[2];
  const float* qw = (const float*)d_in[3];
  const float* lw = (const float*)d_in[4];
  const float* lb = (const float*)d_in[5];
  float* out = (float*)d_out;
  char* ws = (char*)d_ws;

  size_t off = 0;
  auto alloc = [&](size_t bytes) { size_t o = off; off += (bytes + 255) & ~(size_t)255; return o; };
  const size_t o_psum = alloc(16 * 128 * 4);
  const size_t o_psq  = alloc(16 * 128 * 4);
  const size_t o_st   = alloc(16 * 2 * 4);
  const size_t o_qwT  = alloc((size_t)768 * 768 * 2);
  const size_t o_lwB  = alloc((size_t)768 * 256 * 2);
  const size_t o_q    = alloc((size_t)MM * HH * 2);        // 16.8 MB
  const size_t o_kT   = alloc((size_t)BB * HH * PP * 2);   // 16.8 MB
  const size_t o_vT   = alloc((size_t)BB * HH * PP * 2);   // 16.8 MB
  const size_t o_W2   = alloc((size_t)BB * HH * HH * 2);   // 2.1 MB
  const size_t o_M2T  = alloc((size_t)BB * EE * HH * 2);   // 6.3 MB
  const size_t need_base = off;
  const size_t region = (size_t)MM * EE * 2;  // xn (50.3MB) >= part (33.6MB)

  char* big = (ws_size >= need_base + region) ? (ws + need_base) : (char*)d_out;

  float* psum = (float*)(ws + o_psum);
  float* psq  = (float*)(ws + o_psq);
  float* st   = (float*)(ws + o_st);
  u16* qwT    = (u16*)(ws + o_qwT);
  u16* lwB    = (u16*)(ws + o_lwB);
  u16* q_buf  = (u16*)(ws + o_q);
  u16* kT     = (u16*)(ws + o_kT);
  u16* vT     = (u16*)(ws + o_vT);
  u16* W2     = (u16*)(ws + o_W2);
  u16* M2T    = (u16*)(ws + o_M2T);
  u16* xn     = (u16*)big;
  float* part = (float*)big;

  k_reduce1<<<dim3(128, 16), 256, 0, stream>>>(x, psum, psq);
  k_reduce2<<<16, 128, 0, stream>>>(psum, psq, st);
  k_ln<<<2048, 256, 0, stream>>>(x, nw, nb, st, xn);
  k_transpose_w<<<dim3(24, 24), dim3(32, 8), 0, stream>>>(qw, qwT);
  k_cast<<<192, 256, 0, stream>>>(lw, lwB, 768 * 256 / 4);
  k_gemm_qkv8<<<384, 512, 0, stream>>>(xn, qwT, q_buf, kT, vT);
  k_gemm_w2<<<512, 256, 0, stream>>>(kT, vT, part);
  k_reduce_w2<<<4096, 256, 0, stream>>>(part, W2);
  k_gemm_m2<<<192, 256, 0, stream>>>(lwB, W2, M2T);
  k_gemm_out<<<1536, 256, 0, stream>>>(q_buf, M2T, lb, out);
}